// Round 11
// baseline (486.268 us; speedup 1.0000x reference)
//
#include <hip/hip_runtime.h>
#include <hip/hip_bf16.h>

// MeshEdgeBlock fused kernel for MI355X (gfx950).
// R7 (4th resubmit; rounds 7-10 hit infra failures, never measured).
// Software-pipeline GEMM2(nc-1) into GEMM1(nc)'s barrier interval.
// R6 counters: MfmaUtil 20.2, VALUBusy 41, Occ 43 -- each nc was a serial
// chain {GEMM1(global-latency) -> scatter -> barrier -> GEMM2(LDS-latency)}.
// Changes:
//  1) iter nc = { interleaved GEMM2(nc-1) + GEMM1(nc) } -> scatter -> barrier.
//     acc1/acc2 independent chains give ILP across global & LDS pipes.
//  2) ALL next-interval B-frag preloads issued BEFORE scatter+barrier
//     (L2 latency hides under scatter/barrier, not the phase head).
//  3) SiLU division -> v_rcp (exact div was ~10 insts/elem, ~1.3K cyc/wave).
//
// Structure (1 block = 64 edges, 512 threads = 8 waves):
//   X[64x384] staged (as bf16) in LDS in MFMA A-fragment chunk layout.
//   Wave (h,q): rows h*32..+32, cols q*32..+32 (2x2 16x16 MFMA tiles).
//   Epilogue: +b2, LayerNorm (shfl butterfly + LDS combine), +edge residual.

typedef __bf16 bf16;
typedef __bf16 bf16x8 __attribute__((ext_vector_type(8)));
typedef float f32x4 __attribute__((ext_vector_type(4)));

#define E_TOT 250000
#define N_NODES 100000
#define ET 64
#define NBLK ((E_TOT + ET - 1) / ET)  // 3907

// ---------------------------------------------------------------------------
// Prep: pack fp32 row-major weights into bf16 B-fragment layout.
//   W1 [384,512]: W1p[((kb*4+quad)*512 + n)*8 + j] = bf16(W1[(kb*32+quad*8+j)*512 + n])
//   W2 [512,128]: W2p[((kc*4+quad)*128 + n)*8 + j] = bf16(W2[(kc*32+quad*8+j)*128 + n])
// Lane reads are then a single contiguous bf16x8 (16 B) per fragment.
// ---------------------------------------------------------------------------
__global__ __launch_bounds__(256) void pack_weights(const float* __restrict__ W1,
                                                    const float* __restrict__ W2,
                                                    bf16* __restrict__ W1p,
                                                    bf16* __restrict__ W2p) {
  int tid = blockIdx.x * blockDim.x + threadIdx.x;
  if (tid < 384 * 512) {
    int k = tid >> 9;  // row of W1
    int n = tid & 511;
    int kb = k >> 5, quad = (k >> 3) & 3, j = k & 7;
    W1p[(((kb * 4 + quad) * 512) + n) * 8 + j] = (bf16)W1[tid];
  }
  if (tid < 512 * 128) {
    int k = tid >> 7;  // row of W2
    int n = tid & 127;
    int kc = k >> 5, quad = (k >> 3) & 3, j = k & 7;
    W2p[(((kc * 4 + quad) * 128) + n) * 8 + j] = (bf16)W2[tid];
  }
}

#define MFMA16(a, b, c) __builtin_amdgcn_mfma_f32_16x16x32_bf16(a, b, c, 0, 0, 0)

// GEMM1 step kb (K-rows kb*32..+32) at column-chunk nc. Rotating depth-2
// prefetch: bB[kb&1] is consumed, then refilled with step kb+2.
#define G1_STEP(kb, nc)                                                       \
  do {                                                                        \
    bf16x8 a0_ = *(const bf16x8*)(&Xs[((h * 2 + 0) * 12 + (kb)) * 512 + lane * 8]); \
    bf16x8 a1_ = *(const bf16x8*)(&Xs[((h * 2 + 1) * 12 + (kb)) * 512 + lane * 8]); \
    acc1[0][0] = MFMA16(a0_, bB[(kb)&1][0], acc1[0][0]);                      \
    acc1[0][1] = MFMA16(a0_, bB[(kb)&1][1], acc1[0][1]);                      \
    acc1[1][0] = MFMA16(a1_, bB[(kb)&1][0], acc1[1][0]);                      \
    acc1[1][1] = MFMA16(a1_, bB[(kb)&1][1], acc1[1][1]);                      \
    if ((kb) < 10) {                                                          \
      const bf16* wp_ = W1base + ((long)((kb) + 2) * 16384 + (long)(nc)*1024); \
      bB[(kb)&1][0] = *(const bf16x8*)(wp_);                                  \
      bB[(kb)&1][1] = *(const bf16x8*)(wp_ + 128);                            \
    }                                                                         \
  } while (0)

// GEMM2 step kb2 of chunk nc2, reading H from hb.
#define G2_STEP(kb2, nc2, hb)                                                 \
  do {                                                                        \
    bf16x8 a0_ = *(const bf16x8*)(&(hb)[((h * 2 + 0) * 4 + (kb2)) * 512 + lane * 8]); \
    bf16x8 a1_ = *(const bf16x8*)(&(hb)[((h * 2 + 1) * 4 + (kb2)) * 512 + lane * 8]); \
    acc2[0][0] = MFMA16(a0_, bC[(kb2)&1][0], acc2[0][0]);                     \
    acc2[0][1] = MFMA16(a0_, bC[(kb2)&1][1], acc2[0][1]);                     \
    acc2[1][0] = MFMA16(a1_, bC[(kb2)&1][0], acc2[1][0]);                     \
    acc2[1][1] = MFMA16(a1_, bC[(kb2)&1][1], acc2[1][1]);                     \
    if ((kb2) < 2) {                                                          \
      const bf16* wp_ = W2base + ((long)((nc2)*4 + (kb2) + 2) * 4096);        \
      bC[(kb2)&1][0] = *(const bf16x8*)(wp_);                                 \
      bC[(kb2)&1][1] = *(const bf16x8*)(wp_ + 128);                           \
    }                                                                         \
  } while (0)

// bias + SiLU + scatter acc1 into hb's A-frag layout (rcp-based SiLU).
#define SCATTER(hb)                                                           \
  do {                                                                        \
    _Pragma("unroll") for (int i_ = 0; i_ < 2; ++i_)                          \
    _Pragma("unroll") for (int t_ = 0; t_ < 2; ++t_) {                        \
      int pos0_ = ((t_ * 2 + (l15 >> 3)) * 128) + (quad * 4) * 8 + (l15 & 7); \
      bf16* hp_ = &(hb)[((h * 2 + i_) * 4 + q) * 512 + pos0_];                \
      _Pragma("unroll") for (int r_ = 0; r_ < 4; ++r_) {                      \
        float vv_ = acc1[i_][t_][r_] + b1v[t_];                               \
        float s_ = vv_ * __builtin_amdgcn_rcpf(1.0f + __expf(-vv_));          \
        hp_[r_ * 8] = (bf16)s_;                                               \
      }                                                                       \
    }                                                                         \
  } while (0)

__global__ __launch_bounds__(512, 4)
void edge_mlp_kernel(const float* __restrict__ srcf,
                     const float* __restrict__ dstf,
                     const float* __restrict__ edgef,
                     const int* __restrict__ sidx,
                     const int* __restrict__ didx,
                     const bf16* __restrict__ W1p,  // packed B-frag layout
                     const bf16* __restrict__ W2p,  // packed B-frag layout
                     const float* __restrict__ b1p,
                     const float* __restrict__ b2p,
                     const float* __restrict__ gp,
                     const float* __restrict__ bp,
                     float* __restrict__ out) {
  // Xs: 48 chunks (mt*12+kb)*512 bf16, A-frag layout: elem(m,k) at
  //     ((k%32)>>3)*128 + (m%16)*8 + (k%8) within chunk.  48 KB.
  // Hs: 2 buffers x 16 chunks (mt*4+kb2)*512, same layout. 32 KB.
  __shared__ __align__(16) bf16 Xs[48 * 512];
  __shared__ __align__(16) bf16 Hs[2 * 16 * 512];

  const int tid = threadIdx.x;
  const int w = tid >> 6;     // wave 0..7
  const int lane = tid & 63;
  const int l15 = lane & 15;
  const int quad = lane >> 4; // 0..3
  const int h = w >> 2;       // m-half (rows h*32..h*32+31)
  const int q = w & 3;        // n-quarter (cols q*32..q*32+31)
  const long base = (long)blockIdx.x * ET;

  // ---- stage X: wave w handles edge group mt=w&3 (16 edges), kb-half w>>2 ----
  {
    const int mt = w & 3;
    const int half = w >> 2;  // 0: kb 0..5, 1: kb 6..11
    int e = (int)base + mt * 16 + l15;
    int ec = e < E_TOT ? e : (E_TOT - 1);  // clamp tail (stores guarded later)
    int si = sidx[ec];
    int di = didx[ec];
    si = si < 0 ? 0 : (si >= N_NODES ? N_NODES - 1 : si);
    di = di < 0 ? 0 : (di >= N_NODES ? N_NODES - 1 : di);
    const float* rs = srcf + (long)si * 128;
    const float* rd = dstf + (long)di * 128;
    const float* re = edgef + (long)ec * 128;
#pragma unroll
    for (int kk = 0; kk < 6; ++kk) {
      int kb = half * 6 + kk;
      const float* rowp = (kb < 4) ? rs : ((kb < 8) ? rd : re);
      int off = ((kb & 3) << 5) + (quad << 3);  // (kb%4)*32 + quad*8
      float4 v0 = *(const float4*)(rowp + off);
      float4 v1 = *(const float4*)(rowp + off + 4);
      bf16x8 vb;
      vb[0] = (bf16)v0.x; vb[1] = (bf16)v0.y; vb[2] = (bf16)v0.z; vb[3] = (bf16)v0.w;
      vb[4] = (bf16)v1.x; vb[5] = (bf16)v1.y; vb[6] = (bf16)v1.z; vb[7] = (bf16)v1.w;
      // lane (quad*16+l15) holds elems (m=l15, k%32=quad*8..+7): pos=lane*8
      *(bf16x8*)(&Xs[(mt * 12 + kb) * 512 + lane * 8]) = vb;
    }
  }

  // per-lane fixed epilogue columns: n2 = q*32 + t*16 + l15
  float b2v[2], gv[2], bv[2];
#pragma unroll
  for (int t = 0; t < 2; ++t) {
    int n2 = q * 32 + t * 16 + l15;
    b2v[t] = b2p[n2];
    gv[t] = gp[n2];
    bv[t] = bp[n2];
  }

  // per-lane weight base pointers (lane-constant part hoisted once)
  const bf16* W1base = W1p + ((long)quad * 512 + q * 32 + l15) * 8;
  const bf16* W2base = W2p + ((long)quad * 128 + q * 32 + l15) * 8;

  f32x4 acc1[2][2], acc2[2][2];
  bf16x8 bB[2][2], bC[2][2];
  float b1v[2];

#pragma unroll
  for (int i = 0; i < 2; ++i)
#pragma unroll
    for (int t = 0; t < 2; ++t) {
      acc1[i][t] = (f32x4){0.f, 0.f, 0.f, 0.f};
      acc2[i][t] = (f32x4){0.f, 0.f, 0.f, 0.f};
    }

  // preload GEMM1 bB for nc=0, kb=0,1 (issues before the staging barrier:
  // register loads, no LDS dependency -> latency hidden under staging)
#pragma unroll
  for (int p = 0; p < 2; ++p) {
    const bf16* wp_ = W1base + (long)p * 16384;
    bB[p][0] = *(const bf16x8*)(wp_);
    bB[p][1] = *(const bf16x8*)(wp_ + 128);
  }
  b1v[0] = b1p[q * 32 + l15];
  b1v[1] = b1p[q * 32 + 16 + l15];

  __syncthreads();  // Xs staged

  // ---- prologue: GEMM1(0) -> scatter buf0 ----
  G1_STEP(0, 0);  G1_STEP(1, 0);  G1_STEP(2, 0);  G1_STEP(3, 0);
  G1_STEP(4, 0);  G1_STEP(5, 0);  G1_STEP(6, 0);  G1_STEP(7, 0);
  G1_STEP(8, 0);  G1_STEP(9, 0);  G1_STEP(10, 0); G1_STEP(11, 0);

  // preload next interval's weights BEFORE scatter+barrier (hide L2 latency):
  // bB <- (nc=1, kb=0,1); bC <- (nc2=0, kb2=0,1)
#pragma unroll
  for (int p = 0; p < 2; ++p) {
    const bf16* wp1 = W1base + ((long)p * 16384 + 1024);
    bB[p][0] = *(const bf16x8*)(wp1);
    bB[p][1] = *(const bf16x8*)(wp1 + 128);
    const bf16* wp2 = W2base + (long)p * 4096;
    bC[p][0] = *(const bf16x8*)(wp2);
    bC[p][1] = *(const bf16x8*)(wp2 + 128);
  }

  SCATTER(&Hs[0]);
  __syncthreads();

  // ---- pipelined main loop: iter nc = {GEMM2(nc-1) || GEMM1(nc)} ----
#pragma unroll
  for (int nc = 1; nc < 4; ++nc) {
    bf16* hprev = &Hs[((nc - 1) & 1) * 16 * 512];
    bf16* hcur = &Hs[(nc & 1) * 16 * 512];
    b1v[0] = b1p[nc * 128 + q * 32 + l15];
    b1v[1] = b1p[nc * 128 + q * 32 + 16 + l15];
#pragma unroll
    for (int i = 0; i < 2; ++i)
#pragma unroll
      for (int t = 0; t < 2; ++t) acc1[i][t] = (f32x4){0.f, 0.f, 0.f, 0.f};

    // interleave 3 GEMM1 steps : 1 GEMM2 step (independent acc chains)
    G1_STEP(0, nc);  G1_STEP(1, nc);  G1_STEP(2, nc);  G2_STEP(0, nc - 1, hprev);
    G1_STEP(3, nc);  G1_STEP(4, nc);  G1_STEP(5, nc);  G2_STEP(1, nc - 1, hprev);
    G1_STEP(6, nc);  G1_STEP(7, nc);  G1_STEP(8, nc);  G2_STEP(2, nc - 1, hprev);
    G1_STEP(9, nc);  G1_STEP(10, nc); G1_STEP(11, nc); G2_STEP(3, nc - 1, hprev);

    // preload next interval's weights before scatter+barrier
    if (nc < 3) {
#pragma unroll
      for (int p = 0; p < 2; ++p) {
        const bf16* wp1 = W1base + ((long)p * 16384 + (long)(nc + 1) * 1024);
        bB[p][0] = *(const bf16x8*)(wp1);
        bB[p][1] = *(const bf16x8*)(wp1 + 128);
        const bf16* wp2 = W2base + ((long)(nc * 4 + p)) * 4096;
        bC[p][0] = *(const bf16x8*)(wp2);
        bC[p][1] = *(const bf16x8*)(wp2 + 128);
      }
    } else {
#pragma unroll
      for (int p = 0; p < 2; ++p) {
        const bf16* wp2 = W2base + ((long)(12 + p)) * 4096;
        bC[p][0] = *(const bf16x8*)(wp2);
        bC[p][1] = *(const bf16x8*)(wp2 + 128);
      }
    }

    SCATTER(hcur);
    __syncthreads();
  }

  // ---- tail: GEMM2(3) from buf1 ----
  {
    bf16* hb3 = &Hs[1 * 16 * 512];
    G2_STEP(0, 3, hb3);
    G2_STEP(1, 3, hb3);
    G2_STEP(2, 3, hb3);
    G2_STEP(3, 3, hb3);
  }

  // ---- LayerNorm (64 rows); buf0 region reused as scratch ----
  float* psum = (float*)Hs;      // [64][4]
  float* psq = psum + 256;       // [64][4]
  float* pmu = psq + 256;        // [64]
  float* prs = pmu + 64;         // [64]

#pragma unroll
  for (int i = 0; i < 2; ++i) {
#pragma unroll
    for (int r = 0; r < 4; ++r) {
      float v0 = acc2[i][0][r] + b2v[0];
      float v1 = acc2[i][1][r] + b2v[1];
      float s = v0 + v1;
      float ss = v0 * v0 + v1 * v1;
      // butterfly within 16-lane group -> sum of this wave's 32 cols per row
#pragma unroll
      for (int mk = 8; mk >= 1; mk >>= 1) {
        s += __shfl_xor(s, mk, 64);
        ss += __shfl_xor(ss, mk, 64);
      }
      if (l15 == 0) {
        int row = (h * 2 + i) * 16 + quad * 4 + r;
        psum[row * 4 + q] = s;
        psq[row * 4 + q] = ss;
      }
    }
  }
  __syncthreads();
  if (tid < 64) {
    float s = psum[tid * 4] + psum[tid * 4 + 1] + psum[tid * 4 + 2] + psum[tid * 4 + 3];
    float ss = psq[tid * 4] + psq[tid * 4 + 1] + psq[tid * 4 + 2] + psq[tid * 4 + 3];
    float mu = s * (1.0f / 128.0f);
    float var = fmaxf(ss * (1.0f / 128.0f) - mu * mu, 0.0f);  // cancellation-safe
    pmu[tid] = mu;
    prs[tid] = rsqrtf(var + 1e-5f);
  }
  __syncthreads();

  // ---- normalize + gamma/beta + edge residual (from Xs) + store ----
#pragma unroll
  for (int i = 0; i < 2; ++i) {
#pragma unroll
    for (int r = 0; r < 4; ++r) {
      int m = (h * 2 + i) * 16 + quad * 4 + r;
      long e = base + m;
      if (e >= E_TOT) continue;
      float mu = pmu[m];
      float rsg = prs[m];
#pragma unroll
      for (int t = 0; t < 2; ++t) {
        int n2 = q * 32 + t * 16 + l15;
        float v = acc2[i][t][r] + b2v[t];
        int posE = ((t * 2 + (l15 >> 3)) * 128) + (quad * 4 + r) * 8 + (l15 & 7);
        float ev = (float)Xs[((h * 2 + i) * 12 + 8 + q) * 512 + posE];
        float y = (v - mu) * rsg * gv[t] + bv[t] + ev;
        out[e * 128 + n2] = y;
      }
    }
  }
}

extern "C" void kernel_launch(void* const* d_in, const int* in_sizes, int n_in,
                              void* d_out, int out_size, void* d_ws, size_t ws_size,
                              hipStream_t stream) {
  const float* srcf = (const float*)d_in[0];
  const float* dstf = (const float*)d_in[1];
  const float* edgef = (const float*)d_in[2];
  const int* sidx = (const int*)d_in[3];
  const int* didx = (const int*)d_in[4];
  const float* W1 = (const float*)d_in[5];
  const float* b1 = (const float*)d_in[6];
  const float* W2 = (const float*)d_in[7];
  const float* b2 = (const float*)d_in[8];
  const float* g = (const float*)d_in[9];
  const float* be = (const float*)d_in[10];
  float* out = (float*)d_out;

  // Workspace: W1p (384 KB bf16) then W2p (128 KB bf16).
  bf16* W1p = (bf16*)d_ws;
  bf16* W2p = W1p + 384 * 512;

  // Pack weights into MFMA B-fragment layout (cheap: ~1 MB read, 512 KB write).
  pack_weights<<<(384 * 512 + 255) / 256, 256, 0, stream>>>(W1, W2, W1p, W2p);

  edge_mlp_kernel<<<NBLK, 512, 0, stream>>>(srcf, dstf, edgef, sidx, didx,
                                            W1p, W2p, b1, b2, g, be, out);
}